// Round 14
// baseline (42.581 us; speedup 1.0000x reference)
//
#include <hip/hip_runtime.h>
#include <math.h>

#define BATCH 4
#define NPTS  8192
#define TOTAL (BATCH * NPTS)            // 32768 points per set
#define TPB   256

#define WPB    4                        // waves per block
#define ROWS_PER_BLOCK (32 * WPB)       // 128 set1 rows per block
#define COLCH  8                        // set2 sweep chunks
#define SWEEP  (NPTS / COLCH)           // 1024 set2 cols per wave sweep
#define NT     (SWEEP / 32)             // 32 B-tiles per sweep (even)

typedef __bf16 bf16v8 __attribute__((ext_vector_type(8)));
typedef float  f32x16 __attribute__((ext_vector_type(16)));

// ws layout:
//   Af: ushort[TOTAL*16] @ 0    (1 MB)  A-form K-vectors of set1 (rows)
//   Bf: ushort[TOTAL*16] @ 1 MB (1 MB)  B-form K-vectors of set2 (cols)
//   minbuf: uint[2*TOTAL] @ 2 MB (256 KB) dist1 then dist2 (ordered-uint)
//   (2-ahead B prefetch over-reads <=4KB past Bf into minbuf -- mapped, harmless)

__device__ __forceinline__ unsigned f2ord(float f) {
  unsigned b = __float_as_uint(f);
  return ((int)b >= 0) ? (b ^ 0x80000000u) : ~b;
}
__device__ __forceinline__ float ord2f(unsigned k) {
  unsigned b = (k & 0x80000000u) ? (k ^ 0x80000000u) : ~k;
  return __uint_as_float(b);
}
__device__ __forceinline__ unsigned short f2bf(float f) {   // RNE
  unsigned u = __float_as_uint(f);
  return (unsigned short)((u + 0x7fffu + ((u >> 16) & 1u)) >> 16);
}
__device__ __forceinline__ float bf2f(unsigned short h) {
  return __uint_as_float(((unsigned)h) << 16);
}
__device__ __forceinline__ float mf3(float a, float b, float c) {
  return fminf(fminf(a, b), c);   // ISel fuses to v_min3_f32
}

// K-slot pairing (A[k]*B[k]), verified absmax 0 since R4:
//  k0-2: ah*ch   k3-5: al*ch   k6-8: ah*cl   (c = -2b)
//  k9,10: sq_a{h,l} * 1,1      k11,12: 1,1 * sq_b{h,l}     k13-15: 0
__global__ __launch_bounds__(TPB) void pack_kernel(
    const float* __restrict__ x1, const float* __restrict__ x2,
    unsigned short* __restrict__ Af, unsigned short* __restrict__ Bf,
    unsigned* __restrict__ minbuf, float* __restrict__ out) {
  int i = blockIdx.x * TPB + threadIdx.x;   // 0 .. TOTAL-1
  if (i == 0) out[0] = 0.0f;
  minbuf[i] = 0xFFFFFFFFu;
  minbuf[TOTAL + i] = 0xFFFFFFFFu;
  const unsigned short one = 0x3F80;

  // A-form from set1
  {
    float x = x1[3 * i + 0], y = x1[3 * i + 1], z = x1[3 * i + 2];
    float sq = fmaf(x, x, fmaf(y, y, z * z));
    unsigned short sh = f2bf(sq);
    unsigned short sl = f2bf(sq - bf2f(sh));
    unsigned short hx = f2bf(x), hy = f2bf(y), hz = f2bf(z);
    unsigned short lx = f2bf(x - bf2f(hx)), ly = f2bf(y - bf2f(hy)), lz = f2bf(z - bf2f(hz));
    unsigned short v[16] = {hx, hy, hz, lx, ly, lz, hx, hy, hz,
                            sh, sl, one, one, 0, 0, 0};
    uint4* dst = (uint4*)(Af + (size_t)i * 16);
    uint4 w0, w1;
    w0.x = v[0] | ((unsigned)v[1] << 16);  w0.y = v[2] | ((unsigned)v[3] << 16);
    w0.z = v[4] | ((unsigned)v[5] << 16);  w0.w = v[6] | ((unsigned)v[7] << 16);
    w1.x = v[8] | ((unsigned)v[9] << 16);  w1.y = v[10] | ((unsigned)v[11] << 16);
    w1.z = v[12] | ((unsigned)v[13] << 16); w1.w = v[14] | ((unsigned)v[15] << 16);
    dst[0] = w0; dst[1] = w1;
  }
  // B-form from set2
  {
    float x = x2[3 * i + 0], y = x2[3 * i + 1], z = x2[3 * i + 2];
    float sq = fmaf(x, x, fmaf(y, y, z * z));
    unsigned short sh = f2bf(sq);
    unsigned short sl = f2bf(sq - bf2f(sh));
    float cx = -2.0f * x, cy = -2.0f * y, cz = -2.0f * z;
    unsigned short chx = f2bf(cx), chy = f2bf(cy), chz = f2bf(cz);
    unsigned short clx = f2bf(cx - bf2f(chx)), cly = f2bf(cy - bf2f(chy)), clz = f2bf(cz - bf2f(chz));
    unsigned short v[16] = {chx, chy, chz, chx, chy, chz, clx, cly, clz,
                            one, one, sh, sl, 0, 0, 0};
    uint4* dst = (uint4*)(Bf + (size_t)i * 16);
    uint4 w0, w1;
    w0.x = v[0] | ((unsigned)v[1] << 16);  w0.y = v[2] | ((unsigned)v[3] << 16);
    w0.z = v[4] | ((unsigned)v[5] << 16);  w0.w = v[6] | ((unsigned)v[7] << 16);
    w1.x = v[8] | ((unsigned)v[9] << 16);  w1.y = v[10] | ((unsigned)v[11] << 16);
    w1.z = v[12] | ((unsigned)v[13] << 16); w1.w = v[14] | ((unsigned)v[15] << 16);
    dst[0] = w0; dst[1] = w1;
  }
}

// COMBINED single pass, UNCAPPED register budget (no min-waves clause):
// evidence R4 vs R10/R12 says launch_bounds caps push MFMA accs to AGPR
// (gfx90a-style split modeling) -> 3-4x VALU bloat on every acc element
// read. Uncapped, the ~90-reg live set fits the VGPR file.
// Tiles processed in pairs: rowacc[q] = min3(rowacc, accA, accB).
__global__ __launch_bounds__(TPB) void min_kernel(
    const unsigned short* __restrict__ Af, const unsigned short* __restrict__ Bf,
    unsigned* __restrict__ minbuf) {
  __shared__ float colmin[2 * WPB][SWEEP];   // 32 KB
  const int b   = blockIdx.z;
  const int tid = threadIdx.x;
  const int wave = tid >> 6, lane = tid & 63;
  const int g = lane >> 5, l31 = lane & 31;

  const int rowbase = blockIdx.x * ROWS_PER_BLOCK + wave * 32;  // set1 rows
  const int colbase = blockIdx.y * SWEEP;                        // set2 cols

  const bf16v8 af = *((const bf16v8*)Af + (size_t)(b * NPTS + rowbase + l31) * 2 + g);

  f32x16 zc;
#pragma unroll
  for (int q = 0; q < 16; ++q) zc[q] = 0.0f;

  float rowacc[16];
#pragma unroll
  for (int q = 0; q < 16; ++q) rowacc[q] = INFINITY;

  const bf16v8* bp = (const bf16v8*)Bf + (size_t)(b * NPTS + colbase + l31) * 2 + g;
  float* myrow = &colmin[2 * wave + g][0];

  bf16v8 b0 = bp[0], b1 = bp[64];
  for (int ti = 0; ti < NT; ti += 2) {
    f32x16 accA = __builtin_amdgcn_mfma_f32_32x32x16_bf16(af, b0, zc, 0, 0, 0);
    f32x16 accB = __builtin_amdgcn_mfma_f32_32x32x16_bf16(af, b1, zc, 0, 0, 0);
    b0 = bp[128];                          // prefetch tiles ti+2, ti+3
    b1 = bp[192];                          // (tail over-read is mapped ws)

    // dist1: 8 min3 per tile-pair
#pragma unroll
    for (int q = 0; q < 16; ++q)
      rowacc[q] = mf3(rowacc[q], accA[q], accB[q]);

    // dist2: 16->1 fold per tile, plain LDS store (no shfl, no atomic)
    {
      float a0 = mf3(accA[0],  accA[1],  accA[2]);
      float a1 = mf3(accA[3],  accA[4],  accA[5]);
      float a2 = mf3(accA[6],  accA[7],  accA[8]);
      float a3 = mf3(accA[9],  accA[10], accA[11]);
      float a4 = mf3(accA[12], accA[13], accA[14]);
      myrow[ti * 32 + l31] = fminf(mf3(a0, a1, accA[15]), mf3(a2, a3, a4));
    }
    {
      float a0 = mf3(accB[0],  accB[1],  accB[2]);
      float a1 = mf3(accB[3],  accB[4],  accB[5]);
      float a2 = mf3(accB[6],  accB[7],  accB[8]);
      float a3 = mf3(accB[9],  accB[10], accB[11]);
      float a4 = mf3(accB[12], accB[13], accB[14]);
      myrow[(ti + 1) * 32 + l31] = fminf(mf3(a0, a1, accB[15]), mf3(a2, a3, a4));
    }
    bp += 128;
  }

  // dist1 tail: butterfly min across the 32 col-lanes, once per sweep
#pragma unroll
  for (int q = 0; q < 16; ++q) {
    float v = rowacc[q];
    v = fminf(v, __shfl_xor(v, 16));
    v = fminf(v, __shfl_xor(v, 8));
    v = fminf(v, __shfl_xor(v, 4));
    v = fminf(v, __shfl_xor(v, 2));
    v = fminf(v, __shfl_xor(v, 1));
    if (l31 == 0) {
      int row = rowbase + (q & 3) + 8 * (q >> 2) + 4 * g;
      atomicMin(&minbuf[b * NPTS + row], f2ord(v));
    }
  }

  // dist2 flush: fold the 8 half-wave rows, one global atomic per col
  __syncthreads();
  unsigned* __restrict__ d2 = minbuf + TOTAL + b * NPTS + colbase;
  for (int k = tid; k < SWEEP; k += TPB) {
    float m0 = mf3(colmin[0][k], colmin[1][k], colmin[2][k]);
    float m1 = mf3(colmin[3][k], colmin[4][k], colmin[5][k]);
    float m  = fminf(mf3(m0, m1, colmin[6][k]), colmin[7][k]);
    atomicMin(&d2[k], f2ord(m));
  }
}

__global__ __launch_bounds__(TPB) void finalize_kernel(
    const unsigned* __restrict__ minbuf, float* __restrict__ out, float scale) {
  int idx = blockIdx.x * TPB + threadIdx.x;   // 0 .. 2*TOTAL-1
  float v = ord2f(minbuf[idx]) * scale;
  for (int off = 32; off > 0; off >>= 1) v += __shfl_down(v, off);
  __shared__ float ls[TPB / 64];
  if ((threadIdx.x & 63) == 0) ls[threadIdx.x >> 6] = v;
  __syncthreads();
  if (threadIdx.x == 0) {
    float t = 0.0f;
#pragma unroll
    for (int w = 0; w < TPB / 64; ++w) t += ls[w];
    atomicAdd(out, t);
  }
}

extern "C" void kernel_launch(void* const* d_in, const int* in_sizes, int n_in,
                              void* d_out, int out_size, void* d_ws, size_t ws_size,
                              hipStream_t stream) {
  const float* xyz1 = (const float*)d_in[0];
  const float* xyz2 = (const float*)d_in[1];
  float* out = (float*)d_out;

  char* ws = (char*)d_ws;
  unsigned short* Af = (unsigned short*)(ws);
  unsigned short* Bf = (unsigned short*)(ws + (size_t)TOTAL * 32);
  unsigned*   minbuf = (unsigned*)(ws + (size_t)2 * TOTAL * 32);

  // 1) pack set1 A-form + set2 B-form + init minbuf + zero out
  pack_kernel<<<dim3(TOTAL / TPB), dim3(TPB), 0, stream>>>(
      xyz1, xyz2, Af, Bf, minbuf, out);

  // 2) ONE combined pass over the pair space: 64 x 8 x 4 = 2048 blocks
  dim3 mgrid(NPTS / ROWS_PER_BLOCK, COLCH, BATCH);
  min_kernel<<<mgrid, dim3(TPB), 0, stream>>>(Af, Bf, minbuf);

  // 3) finalize: mean(dist1) + mean(dist2)
  const float scale = 1.0f / (float)TOTAL;
  finalize_kernel<<<dim3(2 * TOTAL / TPB), dim3(TPB), 0, stream>>>(minbuf, out, scale);
}

// Round 15
// 30.759 us; speedup vs baseline: 1.3843x; 1.3843x over previous
//
#include <hip/hip_runtime.h>
#include <math.h>

#define BATCH 4
#define NPTS  8192
#define TOTAL (BATCH * NPTS)            // 32768 points per set
#define TPB   256

#define CT     2                        // fixed col-tiles per wave (32 cols each)
#define WPB    (TPB / 64)               // 4 waves per block
#define COLS_PER_WAVE  (32 * CT)        // 64
#define COLS_PER_BLOCK (COLS_PER_WAVE * WPB)  // 256
#define ROWCH  16                       // swept-row chunks
#define SWEEP  (NPTS / ROWCH)           // 512 rows swept per wave
#define NT     (SWEEP / 32)             // 16 A-tiles per sweep

typedef __bf16 bf16v8 __attribute__((ext_vector_type(8)));
typedef float  f32x16 __attribute__((ext_vector_type(16)));

// ws layout:
//   Af: ushort[2*TOTAL*16] @ 0    (2 MB)  A-form K-vectors, set1 then set2
//   Bf: ushort[2*TOTAL*16] @ 2 MB (2 MB)  B-form K-vectors, set1 then set2
//   minbuf: uint[2*TOTAL]  @ 4 MB (256 KB) dist1 then dist2

__device__ __forceinline__ unsigned f2ord(float f) {
  unsigned b = __float_as_uint(f);
  return ((int)b >= 0) ? (b ^ 0x80000000u) : ~b;
}
__device__ __forceinline__ float ord2f(unsigned k) {
  unsigned b = (k & 0x80000000u) ? (k ^ 0x80000000u) : ~k;
  return __uint_as_float(b);
}
__device__ __forceinline__ unsigned short f2bf(float f) {   // RNE
  unsigned u = __float_as_uint(f);
  return (unsigned short)((u + 0x7fffu + ((u >> 16) & 1u)) >> 16);
}
__device__ __forceinline__ float bf2f(unsigned short h) {
  return __uint_as_float(((unsigned)h) << 16);
}
// min3-shaped fminf nesting (ISel fuses to v_min3_f32)
__device__ __forceinline__ float mf3(float a, float b, float c) {
  return fminf(fminf(a, b), c);
}
// min over 16 acc elements folded with carry-in (8 x v_min3)
__device__ __forceinline__ float coltree(const f32x16& a, float colt) {
  float t0 = mf3(a[0], a[1], a[2]);
  float t1 = mf3(a[3], a[4], a[5]);
  float t2 = mf3(a[6], a[7], a[8]);
  float t3 = mf3(a[9], a[10], a[11]);
  float t4 = mf3(a[12], a[13], a[14]);
  return mf3(colt, mf3(t0, t1, a[15]), mf3(t2, t3, t4));
}

// K-slot pairing (A[k]*B[k]), verified absmax 0 since R4:
//  k0-2: ah*ch   k3-5: al*ch   k6-8: ah*cl   (c = -2b)
//  k9,10: sq_a{h,l} * 1,1      k11,12: 1,1 * sq_b{h,l}     k13-15: 0
__global__ __launch_bounds__(TPB) void pack_kernel(
    const float* __restrict__ x1, const float* __restrict__ x2,
    unsigned short* __restrict__ Af, unsigned short* __restrict__ Bf,
    unsigned* __restrict__ minbuf, float* __restrict__ out) {
  int i = blockIdx.x * TPB + threadIdx.x;   // 0 .. 2*TOTAL-1  (set-major)
  if (i == 0) out[0] = 0.0f;
  minbuf[i] = 0xFFFFFFFFu;

  bool s2 = (i >= TOTAL);
  int j = s2 ? i - TOTAL : i;
  const float* src = s2 ? x2 : x1;
  float x = src[3 * j + 0];
  float y = src[3 * j + 1];
  float z = src[3 * j + 2];
  float sq = fmaf(x, x, fmaf(y, y, z * z));
  unsigned short sh = f2bf(sq);
  unsigned short sl = f2bf(sq - bf2f(sh));
  const unsigned short one = 0x3F80;

  unsigned short hx = f2bf(x), hy = f2bf(y), hz = f2bf(z);
  unsigned short lx = f2bf(x - bf2f(hx)), ly = f2bf(y - bf2f(hy)), lz = f2bf(z - bf2f(hz));
  float cx = -2.0f * x, cy = -2.0f * y, cz = -2.0f * z;
  unsigned short chx = f2bf(cx), chy = f2bf(cy), chz = f2bf(cz);
  unsigned short clx = f2bf(cx - bf2f(chx)), cly = f2bf(cy - bf2f(chy)), clz = f2bf(cz - bf2f(chz));

  // A-form
  {
    unsigned short v[16] = {hx, hy, hz, lx, ly, lz, hx, hy, hz,
                            sh, sl, one, one, 0, 0, 0};
    uint4* dst = (uint4*)(Af + (size_t)i * 16);
    uint4 w0, w1;
    w0.x = v[0] | ((unsigned)v[1] << 16);  w0.y = v[2] | ((unsigned)v[3] << 16);
    w0.z = v[4] | ((unsigned)v[5] << 16);  w0.w = v[6] | ((unsigned)v[7] << 16);
    w1.x = v[8] | ((unsigned)v[9] << 16);  w1.y = v[10] | ((unsigned)v[11] << 16);
    w1.z = v[12] | ((unsigned)v[13] << 16); w1.w = v[14] | ((unsigned)v[15] << 16);
    dst[0] = w0; dst[1] = w1;
  }
  // B-form
  {
    unsigned short v[16] = {chx, chy, chz, chx, chy, chz, clx, cly, clz,
                            one, one, sh, sl, 0, 0, 0};
    uint4* dst = (uint4*)(Bf + (size_t)i * 16);
    uint4 w0, w1;
    w0.x = v[0] | ((unsigned)v[1] << 16);  w0.y = v[2] | ((unsigned)v[3] << 16);
    w0.z = v[4] | ((unsigned)v[5] << 16);  w0.w = v[6] | ((unsigned)v[7] << 16);
    w1.x = v[8] | ((unsigned)v[9] << 16);  w1.y = v[10] | ((unsigned)v[11] << 16);
    w1.z = v[12] | ((unsigned)v[13] << 16); w1.w = v[14] | ((unsigned)v[15] << 16);
    dst[0] = w0; dst[1] = w1;
  }
}

// Col-min-only pass, both directions via blockIdx.z (R9 structure, the
// measured champion). R15 delta: FULL unroll with indexed loads so the
// compiler hoists all 16 independent global_load_dwordx4 and folds
// offsets; launch_bounds(256,4) gives the 128-reg budget this needs.
__global__ __launch_bounds__(TPB, 4) void min_kernel(
    const unsigned short* __restrict__ Af, const unsigned short* __restrict__ Bf,
    unsigned* __restrict__ minbuf) {
  const int z   = blockIdx.z;
  const int b   = z & (BATCH - 1);
  const int dir = z >> 2;
  const int tid = threadIdx.x;
  const int wave = tid >> 6, lane = tid & 63;
  const int g = lane >> 5, l31 = lane & 31;

  const int colset = dir * TOTAL;          // offset of the col (target) set
  const int rowset = TOTAL - colset;       // offset of the swept set
  const int colbase = blockIdx.x * COLS_PER_BLOCK + wave * COLS_PER_WAVE;
  const int rowbase = blockIdx.y * SWEEP;

  // fixed B fragments: CT=2 col-tiles
  const bf16v8* bv = (const bf16v8*)Bf;
  bf16v8 bfr0 = bv[(size_t)(colset + b * NPTS + colbase + l31) * 2 + g];
  bf16v8 bfr1 = bv[(size_t)(colset + b * NPTS + colbase + 32 + l31) * 2 + g];

  f32x16 zc;
#pragma unroll
  for (int q = 0; q < 16; ++q) zc[q] = 0.0f;
  float colacc0 = INFINITY, colacc1 = INFINITY;

  const bf16v8* bp = (const bf16v8*)Af + (size_t)(rowset + b * NPTS + rowbase + l31) * 2 + g;

#pragma unroll
  for (int ti = 0; ti < NT; ++ti) {
    bf16v8 a = bp[ti * 64];
    f32x16 acc0 = __builtin_amdgcn_mfma_f32_32x32x16_bf16(a, bfr0, zc, 0, 0, 0);
    f32x16 acc1 = __builtin_amdgcn_mfma_f32_32x32x16_bf16(a, bfr1, zc, 0, 0, 0);
    colacc0 = coltree(acc0, colacc0);
    colacc1 = coltree(acc1, colacc1);
  }

  // tail: merge g-halves (rows split across lane>>5), one masked atomic per tile
  {
    float m0 = fminf(colacc0, __shfl_xor(colacc0, 32));
    float m1 = fminf(colacc1, __shfl_xor(colacc1, 32));
    if (g == 0) {
      atomicMin(&minbuf[colset + b * NPTS + colbase + l31], f2ord(m0));
      atomicMin(&minbuf[colset + b * NPTS + colbase + 32 + l31], f2ord(m1));
    }
  }
}

__global__ __launch_bounds__(TPB) void finalize_kernel(
    const unsigned* __restrict__ minbuf, float* __restrict__ out, float scale) {
  int idx = blockIdx.x * TPB + threadIdx.x;   // 0 .. 2*TOTAL-1
  float v = ord2f(minbuf[idx]) * scale;
  for (int off = 32; off > 0; off >>= 1) v += __shfl_down(v, off);
  __shared__ float ls[TPB / 64];
  if ((threadIdx.x & 63) == 0) ls[threadIdx.x >> 6] = v;
  __syncthreads();
  if (threadIdx.x == 0) {
    float t = 0.0f;
#pragma unroll
    for (int w = 0; w < TPB / 64; ++w) t += ls[w];
    atomicAdd(out, t);
  }
}

extern "C" void kernel_launch(void* const* d_in, const int* in_sizes, int n_in,
                              void* d_out, int out_size, void* d_ws, size_t ws_size,
                              hipStream_t stream) {
  const float* xyz1 = (const float*)d_in[0];
  const float* xyz2 = (const float*)d_in[1];
  float* out = (float*)d_out;

  char* ws = (char*)d_ws;
  unsigned short* Af = (unsigned short*)(ws);
  unsigned short* Bf = (unsigned short*)(ws + (size_t)2 * TOTAL * 32);
  unsigned*   minbuf = (unsigned*)(ws + (size_t)4 * TOTAL * 32);

  // 1) pack A/B forms for both sets + init minbuf + zero out
  pack_kernel<<<dim3(2 * TOTAL / TPB), dim3(TPB), 0, stream>>>(
      xyz1, xyz2, Af, Bf, minbuf, out);

  // 2) both directions, col-min only: 32 x 16 x 8 = 4096 blocks
  dim3 mgrid(NPTS / COLS_PER_BLOCK, ROWCH, 2 * BATCH);
  min_kernel<<<mgrid, dim3(TPB), 0, stream>>>(Af, Bf, minbuf);

  // 3) finalize: mean(dist1) + mean(dist2)
  const float scale = 1.0f / (float)TOTAL;
  finalize_kernel<<<dim3(2 * TOTAL / TPB), dim3(TPB), 0, stream>>>(minbuf, out, scale);
}